// Round 3
// baseline (5335.488 us; speedup 1.0000x reference)
//
#include <hip/hip_runtime.h>

// ---------------------------------------------------------------------------
// LanguageWithAttention: B=2048, V=2000, L=20 (T=19), E=300, ENC=128, DEC=32,
// ATT=128, NPOS=36.  Outputs: preds (B,19,2000) | alphas (B,19,36) | h (B,32).
//
// Pipeline:
//  G1..G3 (lin_gemm): enc (B,36,128) = encoder linears (+dual relu for grid)
//  init_hc:           mean_enc -> h0, c0
//  G4 (lin_gemm):     att1 = enc @ W_enc_att.T + b   (B,36,128)
//  G5 (lin_gemm):     embW = emb_table[cap] @ W_ih[:, :300].T + b_ih  (B,19,128)
//  recurrent_k:       19-step attention+LSTM scan, 4 batch rows per block
//  fc_out:            preds = H @ W_fc.T + b_fc
// ---------------------------------------------------------------------------

__device__ __forceinline__ float dot4f(float4 a, float4 b) {
  return fmaf(a.x, b.x, fmaf(a.y, b.y, fmaf(a.z, b.z, a.w * b.w)));
}
__device__ __forceinline__ float sigmf_(float x) {
  x = fminf(fmaxf(x, -30.f), 30.f);
  return 1.f / (1.f + __expf(-x));
}
__device__ __forceinline__ float tanhf_(float x) {
  x = fminf(fmaxf(x, -15.f), 15.f);
  float e = __expf(2.f * x);
  return (e - 1.f) / (e + 1.f);
}

// ---------------------------------------------------------------------------
// Generic 256-row x 128-col tiled GEMM:  Y[r] = act( X[r] . W[c][0:K] + bias )
// microtile 16x8 (cols split {4tc, 64+4tc}), KB=16.  Optional gather rows
// (emb_table lookup) and optional second input (grid_onehot dual-relu path).
// omode: 0 grid(25/row-group) 1 inv(10) 2 goal 3 flat
// ---------------------------------------------------------------------------
__global__ __launch_bounds__(256, 2) void lin_gemm(
    const float* __restrict__ X, int xstride, const int* __restrict__ gather,
    const float* __restrict__ W, int K, int wstride,
    const float* __restrict__ bias,
    const float* __restrict__ X2, const float* __restrict__ W2,
    const float* __restrict__ bias2,
    float* __restrict__ Y, int omode, int relu) {
  __shared__ __align__(16) float Xs[16 * 260];
  __shared__ __align__(16) float Ws[16 * 132];
  const int tid = threadIdx.x;
  const int tc = tid & 15, tr = tid >> 4;
  const int rbase = blockIdx.x * 256;

  float acc[16][8];
#pragma unroll
  for (int i = 0; i < 16; ++i)
#pragma unroll
    for (int j = 0; j < 8; ++j) acc[i][j] = 0.f;

  for (int k0 = 0; k0 < K; k0 += 16) {
// stage X -> Xs[k][r] (transposed), pad 260
#pragma unroll
    for (int it = 0; it < 4; ++it) {
      int tsk = tid + it * 256;
      int r = tsk >> 2, kq = tsk & 3;
      int rg = rbase + r;
      const float* xrow =
          gather ? (X + (size_t)gather[(rg / 19) * 20 + (rg % 19)] * xstride)
                 : (X + (size_t)rg * xstride);
      int kk = k0 + kq * 4;
      float4 v;
      if (kk + 3 < K)
        v = *(const float4*)(xrow + kk);
      else {
        v.x = (kk + 0 < K) ? xrow[kk + 0] : 0.f;
        v.y = (kk + 1 < K) ? xrow[kk + 1] : 0.f;
        v.z = (kk + 2 < K) ? xrow[kk + 2] : 0.f;
        v.w = (kk + 3 < K) ? xrow[kk + 3] : 0.f;
      }
      Xs[(kq * 4 + 0) * 260 + r] = v.x;
      Xs[(kq * 4 + 1) * 260 + r] = v.y;
      Xs[(kq * 4 + 2) * 260 + r] = v.z;
      Xs[(kq * 4 + 3) * 260 + r] = v.w;
    }
// stage W -> Ws[k][c], pad 132
#pragma unroll
    for (int it = 0; it < 2; ++it) {
      int tsk = tid + it * 256;
      int c = tsk >> 2, kq = tsk & 3;
      const float* wrow = W + (size_t)c * wstride;
      int kk = k0 + kq * 4;
      float4 v;
      if (kk + 3 < K)
        v = *(const float4*)(wrow + kk);
      else {
        v.x = (kk + 0 < K) ? wrow[kk + 0] : 0.f;
        v.y = (kk + 1 < K) ? wrow[kk + 1] : 0.f;
        v.z = (kk + 2 < K) ? wrow[kk + 2] : 0.f;
        v.w = (kk + 3 < K) ? wrow[kk + 3] : 0.f;
      }
      Ws[(kq * 4 + 0) * 132 + c] = v.x;
      Ws[(kq * 4 + 1) * 132 + c] = v.y;
      Ws[(kq * 4 + 2) * 132 + c] = v.z;
      Ws[(kq * 4 + 3) * 132 + c] = v.w;
    }
    __syncthreads();
#pragma unroll
    for (int kk = 0; kk < 16; ++kk) {
      const float* xp = &Xs[kk * 260 + tr * 16];
      float4 xa = *(const float4*)(xp);
      float4 xb = *(const float4*)(xp + 4);
      float4 xc = *(const float4*)(xp + 8);
      float4 xd = *(const float4*)(xp + 12);
      float4 wA = *(const float4*)&Ws[kk * 132 + tc * 4];
      float4 wB = *(const float4*)&Ws[kk * 132 + 64 + tc * 4];
      float xr[16] = {xa.x, xa.y, xa.z, xa.w, xb.x, xb.y, xb.z, xb.w,
                      xc.x, xc.y, xc.z, xc.w, xd.x, xd.y, xd.z, xd.w};
      float wr[8] = {wA.x, wA.y, wA.z, wA.w, wB.x, wB.y, wB.z, wB.w};
#pragma unroll
      for (int i = 0; i < 16; ++i)
#pragma unroll
        for (int j = 0; j < 8; ++j) acc[i][j] = fmaf(xr[i], wr[j], acc[i][j]);
    }
    __syncthreads();
  }

  // optional second (onehot) input: K2 = 7
  float w2r[7][8];
  if (X2) {
#pragma unroll
    for (int k = 0; k < 7; ++k)
      Xs[k * 260 + tid] = X2[(size_t)(rbase + tid) * 7 + k];
#pragma unroll
    for (int it = 0; it < 4; ++it) {
      int tsk = tid + it * 256;
      int c = tsk >> 3, k = tsk & 7;
      if (k < 7) Ws[k * 132 + c] = W2[(size_t)c * 7 + k];
    }
    __syncthreads();
#pragma unroll
    for (int k = 0; k < 7; ++k) {
      float4 a = *(const float4*)&Ws[k * 132 + tc * 4];
      float4 b = *(const float4*)&Ws[k * 132 + 64 + tc * 4];
      w2r[k][0] = a.x; w2r[k][1] = a.y; w2r[k][2] = a.z; w2r[k][3] = a.w;
      w2r[k][4] = b.x; w2r[k][5] = b.y; w2r[k][6] = b.z; w2r[k][7] = b.w;
    }
  }

  float4 bA = *(const float4*)(bias + tc * 4);
  float4 bB = *(const float4*)(bias + 64 + tc * 4);
  float bq[8] = {bA.x, bA.y, bA.z, bA.w, bB.x, bB.y, bB.z, bB.w};
  float b2q[8];
  if (X2) {
    float4 cA = *(const float4*)(bias2 + tc * 4);
    float4 cB = *(const float4*)(bias2 + 64 + tc * 4);
    b2q[0] = cA.x; b2q[1] = cA.y; b2q[2] = cA.z; b2q[3] = cA.w;
    b2q[4] = cB.x; b2q[5] = cB.y; b2q[6] = cB.z; b2q[7] = cB.w;
  }

#pragma unroll
  for (int i = 0; i < 16; ++i) {
    int rg = rbase + tr * 16 + i;
    size_t orow;
    if (omode == 0)
      orow = (size_t)((rg / 25) * 36 + rg % 25) * 128;
    else if (omode == 1)
      orow = (size_t)((rg / 10) * 36 + 25 + rg % 10) * 128;
    else if (omode == 2)
      orow = (size_t)rg * 36 * 128 + 35 * 128;
    else
      orow = (size_t)rg * 128;
    float o[8];
#pragma unroll
    for (int j = 0; j < 8; ++j) {
      float v = acc[i][j] + bq[j];
      if (relu) v = fmaxf(v, 0.f);
      o[j] = v;
    }
    if (X2) {
      float a2[8];
#pragma unroll
      for (int j = 0; j < 8; ++j) a2[j] = b2q[j];
#pragma unroll
      for (int k = 0; k < 7; ++k) {
        float xv = Xs[k * 260 + tr * 16 + i];
#pragma unroll
        for (int j = 0; j < 8; ++j) a2[j] = fmaf(xv, w2r[k][j], a2[j]);
      }
#pragma unroll
      for (int j = 0; j < 8; ++j) o[j] += fmaxf(a2[j], 0.f);
    }
    *(float4*)(Y + orow + tc * 4) = make_float4(o[0], o[1], o[2], o[3]);
    *(float4*)(Y + orow + 64 + tc * 4) = make_float4(o[4], o[5], o[6], o[7]);
  }
}

// ---------------------------------------------------------------------------
// h0/c0 = mean_p enc[b,p,:] @ W_init_{h,c}.T + b.  one 64-thread wave per b.
// ---------------------------------------------------------------------------
__global__ void init_hc(const float* __restrict__ enc,
                        const float* __restrict__ Wh, const float* __restrict__ bh,
                        const float* __restrict__ Wc, const float* __restrict__ bc,
                        float* __restrict__ h0, float* __restrict__ c0) {
  int b = blockIdx.x, l = threadIdx.x;
  __shared__ __align__(16) float mean[128];
  float s0 = 0.f, s1 = 0.f;
  const float* e = enc + (size_t)b * 36 * 128;
  for (int p = 0; p < 36; ++p) {
    s0 += e[p * 128 + l];
    s1 += e[p * 128 + 64 + l];
  }
  mean[l] = s0 * (1.f / 36.f);
  mean[64 + l] = s1 * (1.f / 36.f);
  __syncthreads();
  int k = l & 31;
  const float* Wm = (l < 32) ? Wh : Wc;
  float a = (l < 32) ? bh[k] : bc[k];
#pragma unroll
  for (int c4 = 0; c4 < 32; ++c4) {
    float4 mq = *(const float4*)&mean[c4 * 4];
    float4 wv = *(const float4*)(Wm + (size_t)k * 128 + c4 * 4);
    a += dot4f(mq, wv);
  }
  if (l < 32)
    h0[(size_t)b * 32 + k] = a;
  else
    c0[(size_t)b * 32 + k] = a;
}

// ---------------------------------------------------------------------------
// Recurrent scan.  256 thr = 4 waves; wave w owns batch row b = blk*4 + w.
// LDS (floats, 81920 B total):
//   [0,18432)      enc, 4 rows x [36][128]
//   [18432,18944)  x2 (gate*awe), 4 rows x 128
//   [18944,20480)  12 cross-wave partial slots (w!=r), 128 each.
//     aliases (lifetime-checked): att2[r] = slot((r+1)&3, r)   [pre-barrier1]
//                                 gates/h[r] = slot((r+2)&3, r) [post-barrier2]
// Registers/lane: att1 (72), W_ih[.,300+32w+16s..+16] (64), c (4 @ m<8).
// Per step: A att2+Whh/Wfbeta dots (h bcast from LDS, W from L1) ->
//           B e=relu(att1+att2).wf (att1 in regs; p=lane map, 36=32+4) ->
//           softmax (wave butterfly) -> C awe (enc bcast) -> D gate,x2 ->
//           [bar] E block-coop Wih2 matvec, reg-held weights ->
//           [bar] assemble gates, LSTM pointwise, h->LDS, H->global.
// ---------------------------------------------------------------------------
#define SLOT(w, r) (18944 + (((w) * 3 + ((r) < (w) ? (r) : (r) - 1)) << 7))

__global__ __launch_bounds__(256, 2) void recurrent_k(
    const float* __restrict__ ws_enc, const float* __restrict__ ws_att1,
    const float* __restrict__ ws_embW, const float* __restrict__ ws_h0,
    const float* __restrict__ ws_c0, const float* __restrict__ W_dec_att,
    const float* __restrict__ b_dec_att, const float* __restrict__ W_full_att,
    const float* __restrict__ W_ih, const float* __restrict__ W_hh,
    const float* __restrict__ b_hh, const float* __restrict__ W_fbeta,
    const float* __restrict__ b_fbeta, float* __restrict__ ws_H,
    float* __restrict__ out_alpha, float* __restrict__ out_h) {
  extern __shared__ float lds[];
  const int tid = threadIdx.x;
  const int wave = tid >> 6, lane = tid & 63;
  const int m = lane & 31, s = lane >> 5;
  const int b = blockIdx.x * 4 + wave;

  const int encB = wave * 4608;
  const int x2B = 18432 + wave * 128;
  const int att2B = SLOT((wave + 1) & 3, wave);
  const int ghB = SLOT((wave + 2) & 3, wave);

  // ---- static per-lane registers ----
  float a1m[64];  // att1[b][m][64s+q]
  {
    const float* base = ws_att1 + ((size_t)b * 36 + m) * 128 + 64 * s;
#pragma unroll
    for (int q4 = 0; q4 < 16; ++q4) {
      float4 v = *(const float4*)(base + 4 * q4);
      a1m[4 * q4 + 0] = v.x; a1m[4 * q4 + 1] = v.y;
      a1m[4 * q4 + 2] = v.z; a1m[4 * q4 + 3] = v.w;
    }
  }
  float a1x[8];  // att1[b][32+(lane&3)][(lane>>2)*8+u]
  {
    const float* base =
        ws_att1 + ((size_t)b * 36 + 32 + (lane & 3)) * 128 + (lane >> 2) * 8;
    float4 v0 = *(const float4*)(base);
    float4 v1 = *(const float4*)(base + 4);
    a1x[0] = v0.x; a1x[1] = v0.y; a1x[2] = v0.z; a1x[3] = v0.w;
    a1x[4] = v1.x; a1x[5] = v1.y; a1x[6] = v1.z; a1x[7] = v1.w;
  }
  float wq[4][16];  // W_ih[4m+j][300 + 32*wave + 16*s + q]
#pragma unroll
  for (int j = 0; j < 4; ++j) {
    const float* base =
        W_ih + (size_t)(4 * m + j) * 428 + 300 + 32 * wave + 16 * s;
#pragma unroll
    for (int qq = 0; qq < 4; ++qq) {
      float4 v = *(const float4*)(base + 4 * qq);
      wq[j][4 * qq + 0] = v.x; wq[j][4 * qq + 1] = v.y;
      wq[j][4 * qq + 2] = v.z; wq[j][4 * qq + 3] = v.w;
    }
  }
  const float bdec0 = b_dec_att[lane], bdec1 = b_dec_att[lane + 64];
  float4 bfbq = *(const float4*)(b_fbeta + 4 * m);
  float4 bhhq = *(const float4*)(b_hh + 4 * m);
  float creg[4];
  {
    float4 cq = *(const float4*)(ws_c0 + (size_t)b * 32 + 4 * (m & 7));
    creg[0] = cq.x; creg[1] = cq.y; creg[2] = cq.z; creg[3] = cq.w;
  }

  // ---- stage enc (4 rows) + init h into gh slot ----
  {
    const float* src = ws_enc + (size_t)blockIdx.x * 4 * 4608;
    for (int i = tid; i < 4608; i += 256)
      *(float4*)&lds[i * 4] = *(const float4*)(src + (size_t)i * 4);
  }
  if (m < 8 && s == 0) {
    float4 hq = *(const float4*)(ws_h0 + (size_t)b * 32 + 4 * m);
    *(float4*)&lds[ghB + 4 * m] = hq;
  }
  __syncthreads();

  for (int t = 0; t < 19; ++t) {
    // ---- A: att2[a=lane, lane+64]; fold Whh & Wfbeta partial dots over h ----
    float at2a = bdec0, at2b = bdec1;
    float whhp0 = 0, whhp1 = 0, whhp2 = 0, whhp3 = 0;
    float gatp0 = 0, gatp1 = 0, gatp2 = 0, gatp3 = 0;
#pragma unroll
    for (int kc = 0; kc < 8; ++kc) {
      float4 hq = *(const float4*)&lds[ghB + kc * 4];
      float4 wa = *(const float4*)(W_dec_att + (size_t)lane * 32 + kc * 4);
      float4 wb = *(const float4*)(W_dec_att + (size_t)(lane + 64) * 32 + kc * 4);
      at2a += dot4f(hq, wa);
      at2b += dot4f(hq, wb);
      if ((kc >> 2) == s) {
        float4 w0 = *(const float4*)(W_hh + (size_t)(4 * m + 0) * 32 + kc * 4);
        float4 w1 = *(const float4*)(W_hh + (size_t)(4 * m + 1) * 32 + kc * 4);
        float4 w2 = *(const float4*)(W_hh + (size_t)(4 * m + 2) * 32 + kc * 4);
        float4 w3 = *(const float4*)(W_hh + (size_t)(4 * m + 3) * 32 + kc * 4);
        whhp0 += dot4f(hq, w0); whhp1 += dot4f(hq, w1);
        whhp2 += dot4f(hq, w2); whhp3 += dot4f(hq, w3);
        float4 f0 = *(const float4*)(W_fbeta + (size_t)(4 * m + 0) * 32 + kc * 4);
        float4 f1 = *(const float4*)(W_fbeta + (size_t)(4 * m + 1) * 32 + kc * 4);
        float4 f2 = *(const float4*)(W_fbeta + (size_t)(4 * m + 2) * 32 + kc * 4);
        float4 f3 = *(const float4*)(W_fbeta + (size_t)(4 * m + 3) * 32 + kc * 4);
        gatp0 += dot4f(hq, f0); gatp1 += dot4f(hq, f1);
        gatp2 += dot4f(hq, f2); gatp3 += dot4f(hq, f3);
      }
    }
    lds[att2B + lane] = at2a;
    lds[att2B + 64 + lane] = at2b;

    // ---- B: e[p] = sum_a relu(att1+att2)*wf ----
    float ep = 0.f;
#pragma unroll
    for (int q4 = 0; q4 < 16; ++q4) {
      float4 a2v = *(const float4*)&lds[att2B + 64 * s + 4 * q4];
      float4 wfv = *(const float4*)(W_full_att + 64 * s + 4 * q4);
      ep += fmaxf(a1m[4 * q4 + 0] + a2v.x, 0.f) * wfv.x;
      ep += fmaxf(a1m[4 * q4 + 1] + a2v.y, 0.f) * wfv.y;
      ep += fmaxf(a1m[4 * q4 + 2] + a2v.z, 0.f) * wfv.z;
      ep += fmaxf(a1m[4 * q4 + 3] + a2v.w, 0.f) * wfv.w;
    }
    ep += __shfl_xor(ep, 32);
    float ex2 = 0.f;
    {
      int a0 = (lane >> 2) * 8;
      float4 xa = *(const float4*)&lds[att2B + a0];
      float4 xb = *(const float4*)&lds[att2B + a0 + 4];
      float4 fa = *(const float4*)(W_full_att + a0);
      float4 fb = *(const float4*)(W_full_att + a0 + 4);
      ex2 += fmaxf(a1x[0] + xa.x, 0.f) * fa.x;
      ex2 += fmaxf(a1x[1] + xa.y, 0.f) * fa.y;
      ex2 += fmaxf(a1x[2] + xa.z, 0.f) * fa.z;
      ex2 += fmaxf(a1x[3] + xa.w, 0.f) * fa.w;
      ex2 += fmaxf(a1x[4] + xb.x, 0.f) * fb.x;
      ex2 += fmaxf(a1x[5] + xb.y, 0.f) * fb.y;
      ex2 += fmaxf(a1x[6] + xb.z, 0.f) * fb.z;
      ex2 += fmaxf(a1x[7] + xb.w, 0.f) * fb.w;
      ex2 += __shfl_xor(ex2, 4);
      ex2 += __shfl_xor(ex2, 8);
      ex2 += __shfl_xor(ex2, 16);
      ex2 += __shfl_xor(ex2, 32);
    }
    // softmax over 36 (holder lane p for p<36)
    float ev = (s == 0) ? ep : ((m < 4) ? ex2 : -1e30f);
    float mx = ev;
    mx = fmaxf(mx, __shfl_xor(mx, 1));
    mx = fmaxf(mx, __shfl_xor(mx, 2));
    mx = fmaxf(mx, __shfl_xor(mx, 4));
    mx = fmaxf(mx, __shfl_xor(mx, 8));
    mx = fmaxf(mx, __shfl_xor(mx, 16));
    mx = fmaxf(mx, __shfl_xor(mx, 32));
    float eu = __expf(ev - mx);
    float su = eu;
    su += __shfl_xor(su, 1);
    su += __shfl_xor(su, 2);
    su += __shfl_xor(su, 4);
    su += __shfl_xor(su, 8);
    su += __shfl_xor(su, 16);
    su += __shfl_xor(su, 32);
    float alpha = eu / su;
    {
      size_t ob = ((size_t)b * 19 + t) * 36;
      if (s == 0)
        out_alpha[ob + m] = alpha;
      else if (m < 4)
        out_alpha[ob + 32 + m] = alpha;
    }

    // ---- C: awe[4m+j] = sum_p enc[p][4m+j]*alpha[p], p split by half ----
    float aw0 = 0, aw1 = 0, aw2 = 0, aw3 = 0;
#pragma unroll
    for (int pp = 0; pp < 18; ++pp) {
      float al = __shfl(alpha, 18 * s + pp);
      float4 evv = *(const float4*)&lds[encB + (18 * s + pp) * 128 + 4 * m];
      aw0 += evv.x * al; aw1 += evv.y * al;
      aw2 += evv.z * al; aw3 += evv.w * al;
    }
    aw0 += __shfl_xor(aw0, 32); aw1 += __shfl_xor(aw1, 32);
    aw2 += __shfl_xor(aw2, 32); aw3 += __shfl_xor(aw3, 32);

    // ---- D: gate = sigmoid(.), x2 = gate*awe ----
    float g0 = gatp0 + __shfl_xor(gatp0, 32) + bfbq.x;
    float g1 = gatp1 + __shfl_xor(gatp1, 32) + bfbq.y;
    float g2 = gatp2 + __shfl_xor(gatp2, 32) + bfbq.z;
    float g3 = gatp3 + __shfl_xor(gatp3, 32) + bfbq.w;
    float x20 = sigmf_(g0) * aw0, x21 = sigmf_(g1) * aw1;
    float x22 = sigmf_(g2) * aw2, x23 = sigmf_(g3) * aw3;
    if (s == 0) *(float4*)&lds[x2B + 4 * m] = make_float4(x20, x21, x22, x23);
    __syncthreads();  // barrier 1: all x2 ready

    // ---- E: block-coop Wih2 matvec; wave covers e2 in [32w+16s, +16) ----
    float ownE0 = 0, ownE1 = 0, ownE2 = 0, ownE3 = 0;
#pragma unroll
    for (int rr = 0; rr < 4; ++rr) {
      float p0 = 0, p1 = 0, p2 = 0, p3 = 0;
#pragma unroll
      for (int cc = 0; cc < 4; ++cc) {
        float4 xv = *(const float4*)&lds[18432 + rr * 128 + 32 * wave + 16 * s + 4 * cc];
        p0 += wq[0][4 * cc + 0] * xv.x + wq[0][4 * cc + 1] * xv.y +
              wq[0][4 * cc + 2] * xv.z + wq[0][4 * cc + 3] * xv.w;
        p1 += wq[1][4 * cc + 0] * xv.x + wq[1][4 * cc + 1] * xv.y +
              wq[1][4 * cc + 2] * xv.z + wq[1][4 * cc + 3] * xv.w;
        p2 += wq[2][4 * cc + 0] * xv.x + wq[2][4 * cc + 1] * xv.y +
              wq[2][4 * cc + 2] * xv.z + wq[2][4 * cc + 3] * xv.w;
        p3 += wq[3][4 * cc + 0] * xv.x + wq[3][4 * cc + 1] * xv.y +
              wq[3][4 * cc + 2] * xv.z + wq[3][4 * cc + 3] * xv.w;
      }
      if (rr == wave) {
        ownE0 = p0; ownE1 = p1; ownE2 = p2; ownE3 = p3;
      } else {
        p0 += __shfl_xor(p0, 32); p1 += __shfl_xor(p1, 32);
        p2 += __shfl_xor(p2, 32); p3 += __shfl_xor(p3, 32);
        if (s == 0)
          *(float4*)&lds[SLOT(wave, rr) + 4 * m] = make_float4(p0, p1, p2, p3);
      }
    }
    __syncthreads();  // barrier 2: all partials ready

    // ---- assemble gates for own row; LSTM pointwise ----
    float own0 = ownE0 + whhp0, own1 = ownE1 + whhp1;
    float own2 = ownE2 + whhp2, own3 = ownE3 + whhp3;
    own0 += __shfl_xor(own0, 32); own1 += __shfl_xor(own1, 32);
    own2 += __shfl_xor(own2, 32); own3 += __shfl_xor(own3, 32);
    float4 fA = *(const float4*)&lds[SLOT((wave + 1) & 3, wave) + 4 * m];
    float4 fB = *(const float4*)&lds[SLOT((wave + 2) & 3, wave) + 4 * m];
    float4 fC = *(const float4*)&lds[SLOT((wave + 3) & 3, wave) + 4 * m];
    float4 ew = *(const float4*)(ws_embW + ((size_t)b * 19 + t) * 128 + 4 * m);
    float gg0 = own0 + fA.x + fB.x + fC.x + ew.x + bhhq.x;
    float gg1 = own1 + fA.y + fB.y + fC.y + ew.y + bhhq.y;
    float gg2 = own2 + fA.z + fB.z + fC.z + ew.z + bhhq.z;
    float gg3 = own3 + fA.w + fB.w + fC.w + ew.w + bhhq.w;
    if (s == 0) *(float4*)&lds[ghB + 4 * m] = make_float4(gg0, gg1, gg2, gg3);
    if (m < 8) {
      float4 gi = *(const float4*)&lds[ghB + 4 * m];
      float4 gf = *(const float4*)&lds[ghB + 32 + 4 * m];
      float4 gG = *(const float4*)&lds[ghB + 64 + 4 * m];
      float4 go = *(const float4*)&lds[ghB + 96 + 4 * m];
      float c0n = sigmf_(gf.x) * creg[0] + sigmf_(gi.x) * tanhf_(gG.x);
      float c1n = sigmf_(gf.y) * creg[1] + sigmf_(gi.y) * tanhf_(gG.y);
      float c2n = sigmf_(gf.z) * creg[2] + sigmf_(gi.z) * tanhf_(gG.z);
      float c3n = sigmf_(gf.w) * creg[3] + sigmf_(gi.w) * tanhf_(gG.w);
      float h0n = sigmf_(go.x) * tanhf_(c0n);
      float h1n = sigmf_(go.y) * tanhf_(c1n);
      float h2n = sigmf_(go.z) * tanhf_(c2n);
      float h3n = sigmf_(go.w) * tanhf_(c3n);
      creg[0] = c0n; creg[1] = c1n; creg[2] = c2n; creg[3] = c3n;
      if (s == 0) {
        float4 hv = make_float4(h0n, h1n, h2n, h3n);
        *(float4*)&lds[ghB + 4 * m] = hv;  // h_{t+1} over i-gate region
        *(float4*)(ws_H + ((size_t)b * 19 + t) * 32 + 4 * m) = hv;
        if (t == 18) *(float4*)(out_h + (size_t)b * 32 + 4 * m) = hv;
      }
    }
  }
}

// ---------------------------------------------------------------------------
// preds = H (38912x32) @ W_fc.T (32x2000) + b_fc.  tile 64 rows x 256 cols.
// ---------------------------------------------------------------------------
__global__ __launch_bounds__(256, 2) void fc_out(const float* __restrict__ H,
                                                 const float* __restrict__ W,
                                                 const float* __restrict__ bias,
                                                 float* __restrict__ Y) {
  __shared__ __align__(16) float Hs[32 * 64];
  __shared__ __align__(16) float Wsm[32 * 256];
  const int tid = threadIdx.x;
  const int tc = tid & 31, tr = tid >> 5;
  const int rbase = blockIdx.x * 64;
  const int cbase = blockIdx.y * 256;
#pragma unroll
  for (int it = 0; it < 2; ++it) {
    int tsk = tid + it * 256;
    int r = tsk >> 3, kq = tsk & 7;
    float4 v = *(const float4*)(H + (size_t)(rbase + r) * 32 + kq * 4);
    Hs[(kq * 4 + 0) * 64 + r] = v.x;
    Hs[(kq * 4 + 1) * 64 + r] = v.y;
    Hs[(kq * 4 + 2) * 64 + r] = v.z;
    Hs[(kq * 4 + 3) * 64 + r] = v.w;
  }
#pragma unroll
  for (int it = 0; it < 8; ++it) {
    int tsk = tid + it * 256;
    int c = tsk >> 3, kq = tsk & 7;
    int col = cbase + c;
    float4 v = make_float4(0.f, 0.f, 0.f, 0.f);
    if (col < 2000) v = *(const float4*)(W + (size_t)col * 32 + kq * 4);
    Wsm[(kq * 4 + 0) * 256 + c] = v.x;
    Wsm[(kq * 4 + 1) * 256 + c] = v.y;
    Wsm[(kq * 4 + 2) * 256 + c] = v.z;
    Wsm[(kq * 4 + 3) * 256 + c] = v.w;
  }
  __syncthreads();
  float acc[8][8];
#pragma unroll
  for (int i = 0; i < 8; ++i)
#pragma unroll
    for (int j = 0; j < 8; ++j) acc[i][j] = 0.f;
#pragma unroll
  for (int k = 0; k < 32; ++k) {
    float4 ha = *(const float4*)&Hs[k * 64 + tr * 8];
    float4 hb = *(const float4*)&Hs[k * 64 + tr * 8 + 4];
    float hr[8] = {ha.x, ha.y, ha.z, ha.w, hb.x, hb.y, hb.z, hb.w};
    float2 w0 = *(const float2*)&Wsm[k * 256 + 2 * tc];
    float2 w1 = *(const float2*)&Wsm[k * 256 + 64 + 2 * tc];
    float2 w2 = *(const float2*)&Wsm[k * 256 + 128 + 2 * tc];
    float2 w3 = *(const float2*)&Wsm[k * 256 + 192 + 2 * tc];
    float wc[8] = {w0.x, w0.y, w1.x, w1.y, w2.x, w2.y, w3.x, w3.y};
#pragma unroll
    for (int i = 0; i < 8; ++i)
#pragma unroll
      for (int j = 0; j < 8; ++j) acc[i][j] = fmaf(hr[i], wc[j], acc[i][j]);
  }
  float bq[8];
#pragma unroll
  for (int ch = 0; ch < 4; ++ch) {
    int col = cbase + ch * 64 + 2 * tc;
    bq[2 * ch + 0] = (col < 2000) ? bias[col] : 0.f;
    bq[2 * ch + 1] = (col + 1 < 2000) ? bias[col + 1] : 0.f;
  }
#pragma unroll
  for (int i = 0; i < 8; ++i) {
    size_t row = (size_t)(rbase + tr * 8 + i);
#pragma unroll
    for (int ch = 0; ch < 4; ++ch) {
      int col = cbase + ch * 64 + 2 * tc;
      if (col < 2000) {
        float2 v;
        v.x = acc[i][2 * ch + 0] + bq[2 * ch + 0];
        v.y = acc[i][2 * ch + 1] + bq[2 * ch + 1];
        *(float2*)(Y + row * 2000 + col) = v;
      }
    }
  }
}

// ---------------------------------------------------------------------------
extern "C" void kernel_launch(void* const* d_in, const int* in_sizes, int n_in,
                              void* d_out, int out_size, void* d_ws,
                              size_t ws_size, hipStream_t stream) {
  (void)in_sizes; (void)n_in; (void)out_size; (void)ws_size;
  const float* grid_embedding = (const float*)d_in[0];
  const float* grid_onehot = (const float*)d_in[1];
  const float* inventory = (const float*)d_in[2];
  const float* goal = (const float*)d_in[3];
  const int* captions = (const int*)d_in[4];
  // d_in[5] caption_length == 20 (hardcoded T=19)
  const float* W_embed = (const float*)d_in[6];
  const float* b_embed = (const float*)d_in[7];
  const float* W_onehot = (const float*)d_in[8];
  const float* b_onehot = (const float*)d_in[9];
  const float* W_inv = (const float*)d_in[10];
  const float* b_inv = (const float*)d_in[11];
  const float* W_goal = (const float*)d_in[12];
  const float* b_goal = (const float*)d_in[13];
  const float* W_enc_att = (const float*)d_in[14];
  const float* b_enc_att = (const float*)d_in[15];
  const float* W_dec_att = (const float*)d_in[16];
  const float* b_dec_att = (const float*)d_in[17];
  const float* W_full_att = (const float*)d_in[18];
  // d_in[19] b_full_att: softmax shift-invariant -> unused
  const float* emb_table = (const float*)d_in[20];
  const float* W_ih = (const float*)d_in[21];
  const float* b_ih = (const float*)d_in[22];
  const float* W_hh = (const float*)d_in[23];
  const float* b_hh = (const float*)d_in[24];
  const float* W_init_h = (const float*)d_in[25];
  const float* b_init_h = (const float*)d_in[26];
  const float* W_init_c = (const float*)d_in[27];
  const float* b_init_c = (const float*)d_in[28];
  const float* W_fbeta = (const float*)d_in[29];
  const float* b_fbeta = (const float*)d_in[30];
  const float* W_fc = (const float*)d_in[31];
  const float* b_fc = (const float*)d_in[32];

  float* out = (float*)d_out;
  float* preds = out;                              // 2048*19*2000
  float* alphas = out + (size_t)77824000;          // 2048*19*36
  float* houtp = out + (size_t)79224832;           // 2048*32

  float* ws = (float*)d_ws;
  float* ws_enc = ws;                              // 2048*36*128
  float* ws_att1 = ws_enc + (size_t)9437184;       // 2048*36*128
  float* ws_embW = ws_att1 + (size_t)9437184;      // 2048*19*128
  float* ws_H = ws_embW + (size_t)4980736;         // 2048*19*32
  float* ws_h0 = ws_H + (size_t)1245184;           // 2048*32
  float* ws_c0 = ws_h0 + (size_t)65536;            // 2048*32

  // encoder: grid (dual relu), inventory, goal
  lin_gemm<<<200, 256, 0, stream>>>(grid_embedding, 300, nullptr, W_embed, 300,
                                    300, b_embed, grid_onehot, W_onehot,
                                    b_onehot, ws_enc, 0, 1);
  lin_gemm<<<80, 256, 0, stream>>>(inventory, 300, nullptr, W_inv, 300, 300,
                                   b_inv, nullptr, nullptr, nullptr, ws_enc, 1, 1);
  lin_gemm<<<8, 256, 0, stream>>>(goal, 300, nullptr, W_goal, 300, 300, b_goal,
                                  nullptr, nullptr, nullptr, ws_enc, 2, 1);
  init_hc<<<2048, 64, 0, stream>>>(ws_enc, W_init_h, b_init_h, W_init_c,
                                   b_init_c, ws_h0, ws_c0);
  // att1 = enc @ W_enc_att.T + b
  lin_gemm<<<288, 256, 0, stream>>>(ws_enc, 128, nullptr, W_enc_att, 128, 128,
                                    b_enc_att, nullptr, nullptr, nullptr,
                                    ws_att1, 3, 0);
  // embW = emb_table[cap] @ W_ih[:, :300].T + b_ih
  lin_gemm<<<152, 256, 0, stream>>>(emb_table, 300, captions, W_ih, 300, 428,
                                    b_ih, nullptr, nullptr, nullptr, ws_embW, 3, 0);
  hipFuncSetAttribute((const void*)recurrent_k,
                      hipFuncAttributeMaxDynamicSharedMemorySize, 81920);
  recurrent_k<<<512, 256, 81920, stream>>>(
      ws_enc, ws_att1, ws_embW, ws_h0, ws_c0, W_dec_att, b_dec_att, W_full_att,
      W_ih, W_hh, b_hh, W_fbeta, b_fbeta, ws_H, alphas, houtp);
  fc_out<<<dim3(608, 8), 256, 0, stream>>>(ws_H, W_fc, b_fc, preds);
}

// Round 5
// 1627.447 us; speedup vs baseline: 3.2784x; 3.2784x over previous
//
#include <hip/hip_runtime.h>

// ---------------------------------------------------------------------------
// LanguageWithAttention: B=2048, V=2000, L=20 (T=19), E=300, ENC=128, DEC=32,
// ATT=128, NPOS=36.  Outputs: preds (B,19,2000) | alphas (B,19,36) | h (B,32).
//
// R3 -> R4 change: fc_out rewritten as fc_out2 (W-stationary in LDS, 256
// blocks x 152 full rows each, 2 col-phases).  R3 profile showed old fc_out
// at 3886 us with 14 GB HBM traffic (vs 0.5 GB source-level) -- zero W/H
// reuse across 4864 blocks + whole-buffer-scattered writes.
// R4 -> R5: resubmit unchanged (container infra failure, no counters).
// ---------------------------------------------------------------------------

__device__ __forceinline__ float dot4f(float4 a, float4 b) {
  return fmaf(a.x, b.x, fmaf(a.y, b.y, fmaf(a.z, b.z, a.w * b.w)));
}
__device__ __forceinline__ float sigmf_(float x) {
  x = fminf(fmaxf(x, -30.f), 30.f);
  return 1.f / (1.f + __expf(-x));
}
__device__ __forceinline__ float tanhf_(float x) {
  x = fminf(fmaxf(x, -15.f), 15.f);
  float e = __expf(2.f * x);
  return (e - 1.f) / (e + 1.f);
}

// ---------------------------------------------------------------------------
// Generic 256-row x 128-col tiled GEMM:  Y[r] = act( X[r] . W[c][0:K] + bias )
// microtile 16x8 (cols split {4tc, 64+4tc}), KB=16.  Optional gather rows
// (emb_table lookup) and optional second input (grid_onehot dual-relu path).
// omode: 0 grid(25/row-group) 1 inv(10) 2 goal 3 flat
// ---------------------------------------------------------------------------
__global__ __launch_bounds__(256, 2) void lin_gemm(
    const float* __restrict__ X, int xstride, const int* __restrict__ gather,
    const float* __restrict__ W, int K, int wstride,
    const float* __restrict__ bias,
    const float* __restrict__ X2, const float* __restrict__ W2,
    const float* __restrict__ bias2,
    float* __restrict__ Y, int omode, int relu) {
  __shared__ __align__(16) float Xs[16 * 260];
  __shared__ __align__(16) float Ws[16 * 132];
  const int tid = threadIdx.x;
  const int tc = tid & 15, tr = tid >> 4;
  const int rbase = blockIdx.x * 256;

  float acc[16][8];
#pragma unroll
  for (int i = 0; i < 16; ++i)
#pragma unroll
    for (int j = 0; j < 8; ++j) acc[i][j] = 0.f;

  for (int k0 = 0; k0 < K; k0 += 16) {
// stage X -> Xs[k][r] (transposed), pad 260
#pragma unroll
    for (int it = 0; it < 4; ++it) {
      int tsk = tid + it * 256;
      int r = tsk >> 2, kq = tsk & 3;
      int rg = rbase + r;
      const float* xrow =
          gather ? (X + (size_t)gather[(rg / 19) * 20 + (rg % 19)] * xstride)
                 : (X + (size_t)rg * xstride);
      int kk = k0 + kq * 4;
      float4 v;
      if (kk + 3 < K)
        v = *(const float4*)(xrow + kk);
      else {
        v.x = (kk + 0 < K) ? xrow[kk + 0] : 0.f;
        v.y = (kk + 1 < K) ? xrow[kk + 1] : 0.f;
        v.z = (kk + 2 < K) ? xrow[kk + 2] : 0.f;
        v.w = (kk + 3 < K) ? xrow[kk + 3] : 0.f;
      }
      Xs[(kq * 4 + 0) * 260 + r] = v.x;
      Xs[(kq * 4 + 1) * 260 + r] = v.y;
      Xs[(kq * 4 + 2) * 260 + r] = v.z;
      Xs[(kq * 4 + 3) * 260 + r] = v.w;
    }
// stage W -> Ws[k][c], pad 132
#pragma unroll
    for (int it = 0; it < 2; ++it) {
      int tsk = tid + it * 256;
      int c = tsk >> 2, kq = tsk & 3;
      const float* wrow = W + (size_t)c * wstride;
      int kk = k0 + kq * 4;
      float4 v;
      if (kk + 3 < K)
        v = *(const float4*)(wrow + kk);
      else {
        v.x = (kk + 0 < K) ? wrow[kk + 0] : 0.f;
        v.y = (kk + 1 < K) ? wrow[kk + 1] : 0.f;
        v.z = (kk + 2 < K) ? wrow[kk + 2] : 0.f;
        v.w = (kk + 3 < K) ? wrow[kk + 3] : 0.f;
      }
      Ws[(kq * 4 + 0) * 132 + c] = v.x;
      Ws[(kq * 4 + 1) * 132 + c] = v.y;
      Ws[(kq * 4 + 2) * 132 + c] = v.z;
      Ws[(kq * 4 + 3) * 132 + c] = v.w;
    }
    __syncthreads();
#pragma unroll
    for (int kk = 0; kk < 16; ++kk) {
      const float* xp = &Xs[kk * 260 + tr * 16];
      float4 xa = *(const float4*)(xp);
      float4 xb = *(const float4*)(xp + 4);
      float4 xc = *(const float4*)(xp + 8);
      float4 xd = *(const float4*)(xp + 12);
      float4 wA = *(const float4*)&Ws[kk * 132 + tc * 4];
      float4 wB = *(const float4*)&Ws[kk * 132 + 64 + tc * 4];
      float xr[16] = {xa.x, xa.y, xa.z, xa.w, xb.x, xb.y, xb.z, xb.w,
                      xc.x, xc.y, xc.z, xc.w, xd.x, xd.y, xd.z, xd.w};
      float wr[8] = {wA.x, wA.y, wA.z, wA.w, wB.x, wB.y, wB.z, wB.w};
#pragma unroll
      for (int i = 0; i < 16; ++i)
#pragma unroll
        for (int j = 0; j < 8; ++j) acc[i][j] = fmaf(xr[i], wr[j], acc[i][j]);
    }
    __syncthreads();
  }

  // optional second (onehot) input: K2 = 7
  float w2r[7][8];
  if (X2) {
#pragma unroll
    for (int k = 0; k < 7; ++k)
      Xs[k * 260 + tid] = X2[(size_t)(rbase + tid) * 7 + k];
#pragma unroll
    for (int it = 0; it < 4; ++it) {
      int tsk = tid + it * 256;
      int c = tsk >> 3, k = tsk & 7;
      if (k < 7) Ws[k * 132 + c] = W2[(size_t)c * 7 + k];
    }
    __syncthreads();
#pragma unroll
    for (int k = 0; k < 7; ++k) {
      float4 a = *(const float4*)&Ws[k * 132 + tc * 4];
      float4 b = *(const float4*)&Ws[k * 132 + 64 + tc * 4];
      w2r[k][0] = a.x; w2r[k][1] = a.y; w2r[k][2] = a.z; w2r[k][3] = a.w;
      w2r[k][4] = b.x; w2r[k][5] = b.y; w2r[k][6] = b.z; w2r[k][7] = b.w;
    }
  }

  float4 bA = *(const float4*)(bias + tc * 4);
  float4 bB = *(const float4*)(bias + 64 + tc * 4);
  float bq[8] = {bA.x, bA.y, bA.z, bA.w, bB.x, bB.y, bB.z, bB.w};
  float b2q[8];
  if (X2) {
    float4 cA = *(const float4*)(bias2 + tc * 4);
    float4 cB = *(const float4*)(bias2 + 64 + tc * 4);
    b2q[0] = cA.x; b2q[1] = cA.y; b2q[2] = cA.z; b2q[3] = cA.w;
    b2q[4] = cB.x; b2q[5] = cB.y; b2q[6] = cB.z; b2q[7] = cB.w;
  }

#pragma unroll
  for (int i = 0; i < 16; ++i) {
    int rg = rbase + tr * 16 + i;
    size_t orow;
    if (omode == 0)
      orow = (size_t)((rg / 25) * 36 + rg % 25) * 128;
    else if (omode == 1)
      orow = (size_t)((rg / 10) * 36 + 25 + rg % 10) * 128;
    else if (omode == 2)
      orow = (size_t)rg * 36 * 128 + 35 * 128;
    else
      orow = (size_t)rg * 128;
    float o[8];
#pragma unroll
    for (int j = 0; j < 8; ++j) {
      float v = acc[i][j] + bq[j];
      if (relu) v = fmaxf(v, 0.f);
      o[j] = v;
    }
    if (X2) {
      float a2[8];
#pragma unroll
      for (int j = 0; j < 8; ++j) a2[j] = b2q[j];
#pragma unroll
      for (int k = 0; k < 7; ++k) {
        float xv = Xs[k * 260 + tr * 16 + i];
#pragma unroll
        for (int j = 0; j < 8; ++j) a2[j] = fmaf(xv, w2r[k][j], a2[j]);
      }
#pragma unroll
      for (int j = 0; j < 8; ++j) o[j] += fmaxf(a2[j], 0.f);
    }
    *(float4*)(Y + orow + tc * 4) = make_float4(o[0], o[1], o[2], o[3]);
    *(float4*)(Y + orow + 64 + tc * 4) = make_float4(o[4], o[5], o[6], o[7]);
  }
}

// ---------------------------------------------------------------------------
// h0/c0 = mean_p enc[b,p,:] @ W_init_{h,c}.T + b.  one 64-thread wave per b.
// ---------------------------------------------------------------------------
__global__ void init_hc(const float* __restrict__ enc,
                        const float* __restrict__ Wh, const float* __restrict__ bh,
                        const float* __restrict__ Wc, const float* __restrict__ bc,
                        float* __restrict__ h0, float* __restrict__ c0) {
  int b = blockIdx.x, l = threadIdx.x;
  __shared__ __align__(16) float mean[128];
  float s0 = 0.f, s1 = 0.f;
  const float* e = enc + (size_t)b * 36 * 128;
  for (int p = 0; p < 36; ++p) {
    s0 += e[p * 128 + l];
    s1 += e[p * 128 + 64 + l];
  }
  mean[l] = s0 * (1.f / 36.f);
  mean[64 + l] = s1 * (1.f / 36.f);
  __syncthreads();
  int k = l & 31;
  const float* Wm = (l < 32) ? Wh : Wc;
  float a = (l < 32) ? bh[k] : bc[k];
#pragma unroll
  for (int c4 = 0; c4 < 32; ++c4) {
    float4 mq = *(const float4*)&mean[c4 * 4];
    float4 wv = *(const float4*)(Wm + (size_t)k * 128 + c4 * 4);
    a += dot4f(mq, wv);
  }
  if (l < 32)
    h0[(size_t)b * 32 + k] = a;
  else
    c0[(size_t)b * 32 + k] = a;
}

// ---------------------------------------------------------------------------
// Recurrent scan.  256 thr = 4 waves; wave w owns batch row b = blk*4 + w.
// (unchanged from R3 -- passed verification)
// ---------------------------------------------------------------------------
#define SLOT(w, r) (18944 + (((w) * 3 + ((r) < (w) ? (r) : (r) - 1)) << 7))

__global__ __launch_bounds__(256, 2) void recurrent_k(
    const float* __restrict__ ws_enc, const float* __restrict__ ws_att1,
    const float* __restrict__ ws_embW, const float* __restrict__ ws_h0,
    const float* __restrict__ ws_c0, const float* __restrict__ W_dec_att,
    const float* __restrict__ b_dec_att, const float* __restrict__ W_full_att,
    const float* __restrict__ W_ih, const float* __restrict__ W_hh,
    const float* __restrict__ b_hh, const float* __restrict__ W_fbeta,
    const float* __restrict__ b_fbeta, float* __restrict__ ws_H,
    float* __restrict__ out_alpha, float* __restrict__ out_h) {
  extern __shared__ float lds[];
  const int tid = threadIdx.x;
  const int wave = tid >> 6, lane = tid & 63;
  const int m = lane & 31, s = lane >> 5;
  const int b = blockIdx.x * 4 + wave;

  const int encB = wave * 4608;
  const int x2B = 18432 + wave * 128;
  const int att2B = SLOT((wave + 1) & 3, wave);
  const int ghB = SLOT((wave + 2) & 3, wave);

  // ---- static per-lane registers ----
  float a1m[64];  // att1[b][m][64s+q]
  {
    const float* base = ws_att1 + ((size_t)b * 36 + m) * 128 + 64 * s;
#pragma unroll
    for (int q4 = 0; q4 < 16; ++q4) {
      float4 v = *(const float4*)(base + 4 * q4);
      a1m[4 * q4 + 0] = v.x; a1m[4 * q4 + 1] = v.y;
      a1m[4 * q4 + 2] = v.z; a1m[4 * q4 + 3] = v.w;
    }
  }
  float a1x[8];  // att1[b][32+(lane&3)][(lane>>2)*8+u]
  {
    const float* base =
        ws_att1 + ((size_t)b * 36 + 32 + (lane & 3)) * 128 + (lane >> 2) * 8;
    float4 v0 = *(const float4*)(base);
    float4 v1 = *(const float4*)(base + 4);
    a1x[0] = v0.x; a1x[1] = v0.y; a1x[2] = v0.z; a1x[3] = v0.w;
    a1x[4] = v1.x; a1x[5] = v1.y; a1x[6] = v1.z; a1x[7] = v1.w;
  }
  float wq[4][16];  // W_ih[4m+j][300 + 32*wave + 16*s + q]
#pragma unroll
  for (int j = 0; j < 4; ++j) {
    const float* base =
        W_ih + (size_t)(4 * m + j) * 428 + 300 + 32 * wave + 16 * s;
#pragma unroll
    for (int qq = 0; qq < 4; ++qq) {
      float4 v = *(const float4*)(base + 4 * qq);
      wq[j][4 * qq + 0] = v.x; wq[j][4 * qq + 1] = v.y;
      wq[j][4 * qq + 2] = v.z; wq[j][4 * qq + 3] = v.w;
    }
  }
  const float bdec0 = b_dec_att[lane], bdec1 = b_dec_att[lane + 64];
  float4 bfbq = *(const float4*)(b_fbeta + 4 * m);
  float4 bhhq = *(const float4*)(b_hh + 4 * m);
  float creg[4];
  {
    float4 cq = *(const float4*)(ws_c0 + (size_t)b * 32 + 4 * (m & 7));
    creg[0] = cq.x; creg[1] = cq.y; creg[2] = cq.z; creg[3] = cq.w;
  }

  // ---- stage enc (4 rows) + init h into gh slot ----
  {
    const float* src = ws_enc + (size_t)blockIdx.x * 4 * 4608;
    for (int i = tid; i < 4608; i += 256)
      *(float4*)&lds[i * 4] = *(const float4*)(src + (size_t)i * 4);
  }
  if (m < 8 && s == 0) {
    float4 hq = *(const float4*)(ws_h0 + (size_t)b * 32 + 4 * m);
    *(float4*)&lds[ghB + 4 * m] = hq;
  }
  __syncthreads();

  for (int t = 0; t < 19; ++t) {
    // ---- A: att2[a=lane, lane+64]; fold Whh & Wfbeta partial dots over h ----
    float at2a = bdec0, at2b = bdec1;
    float whhp0 = 0, whhp1 = 0, whhp2 = 0, whhp3 = 0;
    float gatp0 = 0, gatp1 = 0, gatp2 = 0, gatp3 = 0;
#pragma unroll
    for (int kc = 0; kc < 8; ++kc) {
      float4 hq = *(const float4*)&lds[ghB + kc * 4];
      float4 wa = *(const float4*)(W_dec_att + (size_t)lane * 32 + kc * 4);
      float4 wb = *(const float4*)(W_dec_att + (size_t)(lane + 64) * 32 + kc * 4);
      at2a += dot4f(hq, wa);
      at2b += dot4f(hq, wb);
      if ((kc >> 2) == s) {
        float4 w0 = *(const float4*)(W_hh + (size_t)(4 * m + 0) * 32 + kc * 4);
        float4 w1 = *(const float4*)(W_hh + (size_t)(4 * m + 1) * 32 + kc * 4);
        float4 w2 = *(const float4*)(W_hh + (size_t)(4 * m + 2) * 32 + kc * 4);
        float4 w3 = *(const float4*)(W_hh + (size_t)(4 * m + 3) * 32 + kc * 4);
        whhp0 += dot4f(hq, w0); whhp1 += dot4f(hq, w1);
        whhp2 += dot4f(hq, w2); whhp3 += dot4f(hq, w3);
        float4 f0 = *(const float4*)(W_fbeta + (size_t)(4 * m + 0) * 32 + kc * 4);
        float4 f1 = *(const float4*)(W_fbeta + (size_t)(4 * m + 1) * 32 + kc * 4);
        float4 f2 = *(const float4*)(W_fbeta + (size_t)(4 * m + 2) * 32 + kc * 4);
        float4 f3 = *(const float4*)(W_fbeta + (size_t)(4 * m + 3) * 32 + kc * 4);
        gatp0 += dot4f(hq, f0); gatp1 += dot4f(hq, f1);
        gatp2 += dot4f(hq, f2); gatp3 += dot4f(hq, f3);
      }
    }
    lds[att2B + lane] = at2a;
    lds[att2B + 64 + lane] = at2b;

    // ---- B: e[p] = sum_a relu(att1+att2)*wf ----
    float ep = 0.f;
#pragma unroll
    for (int q4 = 0; q4 < 16; ++q4) {
      float4 a2v = *(const float4*)&lds[att2B + 64 * s + 4 * q4];
      float4 wfv = *(const float4*)(W_full_att + 64 * s + 4 * q4);
      ep += fmaxf(a1m[4 * q4 + 0] + a2v.x, 0.f) * wfv.x;
      ep += fmaxf(a1m[4 * q4 + 1] + a2v.y, 0.f) * wfv.y;
      ep += fmaxf(a1m[4 * q4 + 2] + a2v.z, 0.f) * wfv.z;
      ep += fmaxf(a1m[4 * q4 + 3] + a2v.w, 0.f) * wfv.w;
    }
    ep += __shfl_xor(ep, 32);
    float ex2 = 0.f;
    {
      int a0 = (lane >> 2) * 8;
      float4 xa = *(const float4*)&lds[att2B + a0];
      float4 xb = *(const float4*)&lds[att2B + a0 + 4];
      float4 fa = *(const float4*)(W_full_att + a0);
      float4 fb = *(const float4*)(W_full_att + a0 + 4);
      ex2 += fmaxf(a1x[0] + xa.x, 0.f) * fa.x;
      ex2 += fmaxf(a1x[1] + xa.y, 0.f) * fa.y;
      ex2 += fmaxf(a1x[2] + xa.z, 0.f) * fa.z;
      ex2 += fmaxf(a1x[3] + xa.w, 0.f) * fa.w;
      ex2 += fmaxf(a1x[4] + xb.x, 0.f) * fb.x;
      ex2 += fmaxf(a1x[5] + xb.y, 0.f) * fb.y;
      ex2 += fmaxf(a1x[6] + xb.z, 0.f) * fb.z;
      ex2 += fmaxf(a1x[7] + xb.w, 0.f) * fb.w;
      ex2 += __shfl_xor(ex2, 4);
      ex2 += __shfl_xor(ex2, 8);
      ex2 += __shfl_xor(ex2, 16);
      ex2 += __shfl_xor(ex2, 32);
    }
    // softmax over 36 (holder lane p for p<36)
    float ev = (s == 0) ? ep : ((m < 4) ? ex2 : -1e30f);
    float mx = ev;
    mx = fmaxf(mx, __shfl_xor(mx, 1));
    mx = fmaxf(mx, __shfl_xor(mx, 2));
    mx = fmaxf(mx, __shfl_xor(mx, 4));
    mx = fmaxf(mx, __shfl_xor(mx, 8));
    mx = fmaxf(mx, __shfl_xor(mx, 16));
    mx = fmaxf(mx, __shfl_xor(mx, 32));
    float eu = __expf(ev - mx);
    float su = eu;
    su += __shfl_xor(su, 1);
    su += __shfl_xor(su, 2);
    su += __shfl_xor(su, 4);
    su += __shfl_xor(su, 8);
    su += __shfl_xor(su, 16);
    su += __shfl_xor(su, 32);
    float alpha = eu / su;
    {
      size_t ob = ((size_t)b * 19 + t) * 36;
      if (s == 0)
        out_alpha[ob + m] = alpha;
      else if (m < 4)
        out_alpha[ob + 32 + m] = alpha;
    }

    // ---- C: awe[4m+j] = sum_p enc[p][4m+j]*alpha[p], p split by half ----
    float aw0 = 0, aw1 = 0, aw2 = 0, aw3 = 0;
#pragma unroll
    for (int pp = 0; pp < 18; ++pp) {
      float al = __shfl(alpha, 18 * s + pp);
      float4 evv = *(const float4*)&lds[encB + (18 * s + pp) * 128 + 4 * m];
      aw0 += evv.x * al; aw1 += evv.y * al;
      aw2 += evv.z * al; aw3 += evv.w * al;
    }
    aw0 += __shfl_xor(aw0, 32); aw1 += __shfl_xor(aw1, 32);
    aw2 += __shfl_xor(aw2, 32); aw3 += __shfl_xor(aw3, 32);

    // ---- D: gate = sigmoid(.), x2 = gate*awe ----
    float g0 = gatp0 + __shfl_xor(gatp0, 32) + bfbq.x;
    float g1 = gatp1 + __shfl_xor(gatp1, 32) + bfbq.y;
    float g2 = gatp2 + __shfl_xor(gatp2, 32) + bfbq.z;
    float g3 = gatp3 + __shfl_xor(gatp3, 32) + bfbq.w;
    float x20 = sigmf_(g0) * aw0, x21 = sigmf_(g1) * aw1;
    float x22 = sigmf_(g2) * aw2, x23 = sigmf_(g3) * aw3;
    if (s == 0) *(float4*)&lds[x2B + 4 * m] = make_float4(x20, x21, x22, x23);
    __syncthreads();  // barrier 1: all x2 ready

    // ---- E: block-coop Wih2 matvec; wave covers e2 in [32w+16s, +16) ----
    float ownE0 = 0, ownE1 = 0, ownE2 = 0, ownE3 = 0;
#pragma unroll
    for (int rr = 0; rr < 4; ++rr) {
      float p0 = 0, p1 = 0, p2 = 0, p3 = 0;
#pragma unroll
      for (int cc = 0; cc < 4; ++cc) {
        float4 xv = *(const float4*)&lds[18432 + rr * 128 + 32 * wave + 16 * s + 4 * cc];
        p0 += wq[0][4 * cc + 0] * xv.x + wq[0][4 * cc + 1] * xv.y +
              wq[0][4 * cc + 2] * xv.z + wq[0][4 * cc + 3] * xv.w;
        p1 += wq[1][4 * cc + 0] * xv.x + wq[1][4 * cc + 1] * xv.y +
              wq[1][4 * cc + 2] * xv.z + wq[1][4 * cc + 3] * xv.w;
        p2 += wq[2][4 * cc + 0] * xv.x + wq[2][4 * cc + 1] * xv.y +
              wq[2][4 * cc + 2] * xv.z + wq[2][4 * cc + 3] * xv.w;
        p3 += wq[3][4 * cc + 0] * xv.x + wq[3][4 * cc + 1] * xv.y +
              wq[3][4 * cc + 2] * xv.z + wq[3][4 * cc + 3] * xv.w;
      }
      if (rr == wave) {
        ownE0 = p0; ownE1 = p1; ownE2 = p2; ownE3 = p3;
      } else {
        p0 += __shfl_xor(p0, 32); p1 += __shfl_xor(p1, 32);
        p2 += __shfl_xor(p2, 32); p3 += __shfl_xor(p3, 32);
        if (s == 0)
          *(float4*)&lds[SLOT(wave, rr) + 4 * m] = make_float4(p0, p1, p2, p3);
      }
    }
    __syncthreads();  // barrier 2: all partials ready

    // ---- assemble gates for own row; LSTM pointwise ----
    float own0 = ownE0 + whhp0, own1 = ownE1 + whhp1;
    float own2 = ownE2 + whhp2, own3 = ownE3 + whhp3;
    own0 += __shfl_xor(own0, 32); own1 += __shfl_xor(own1, 32);
    own2 += __shfl_xor(own2, 32); own3 += __shfl_xor(own3, 32);
    float4 fA = *(const float4*)&lds[SLOT((wave + 1) & 3, wave) + 4 * m];
    float4 fB = *(const float4*)&lds[SLOT((wave + 2) & 3, wave) + 4 * m];
    float4 fC = *(const float4*)&lds[SLOT((wave + 3) & 3, wave) + 4 * m];
    float4 ew = *(const float4*)(ws_embW + ((size_t)b * 19 + t) * 128 + 4 * m);
    float gg0 = own0 + fA.x + fB.x + fC.x + ew.x + bhhq.x;
    float gg1 = own1 + fA.y + fB.y + fC.y + ew.y + bhhq.y;
    float gg2 = own2 + fA.z + fB.z + fC.z + ew.z + bhhq.z;
    float gg3 = own3 + fA.w + fB.w + fC.w + ew.w + bhhq.w;
    if (s == 0) *(float4*)&lds[ghB + 4 * m] = make_float4(gg0, gg1, gg2, gg3);
    if (m < 8) {
      float4 gi = *(const float4*)&lds[ghB + 4 * m];
      float4 gf = *(const float4*)&lds[ghB + 32 + 4 * m];
      float4 gG = *(const float4*)&lds[ghB + 64 + 4 * m];
      float4 go = *(const float4*)&lds[ghB + 96 + 4 * m];
      float c0n = sigmf_(gf.x) * creg[0] + sigmf_(gi.x) * tanhf_(gG.x);
      float c1n = sigmf_(gf.y) * creg[1] + sigmf_(gi.y) * tanhf_(gG.y);
      float c2n = sigmf_(gf.z) * creg[2] + sigmf_(gi.z) * tanhf_(gG.z);
      float c3n = sigmf_(gf.w) * creg[3] + sigmf_(gi.w) * tanhf_(gG.w);
      float h0n = sigmf_(go.x) * tanhf_(c0n);
      float h1n = sigmf_(go.y) * tanhf_(c1n);
      float h2n = sigmf_(go.z) * tanhf_(c2n);
      float h3n = sigmf_(go.w) * tanhf_(c3n);
      creg[0] = c0n; creg[1] = c1n; creg[2] = c2n; creg[3] = c3n;
      if (s == 0) {
        float4 hv = make_float4(h0n, h1n, h2n, h3n);
        *(float4*)&lds[ghB + 4 * m] = hv;  // h_{t+1} over i-gate region
        *(float4*)(ws_H + ((size_t)b * 19 + t) * 32 + 4 * m) = hv;
        if (t == 18) *(float4*)(out_h + (size_t)b * 32 + 4 * m) = hv;
      }
    }
  }
}

// ---------------------------------------------------------------------------
// fc_out2: preds = H (38912x32) @ W_fc.T (32x2000) + b_fc.
// 256 blocks x 512 thr; block owns 152 FULL rows (256*152=38912 exact).
// W_fc staged transposed in LDS in 2 phases (cols [0,1024) then [1024,2000)),
// reused across all 152 rows; H tile staged once (transposed).
// LDS: Wt[32][1026] (131328 B) + Hs[32][154] (19712 B) = 151040 B -> 1 blk/CU.
// Thread tile: 8 rows x 8 cols (4 chunks of float2, lanes stride-2 -> ~2-way
// LDS aliasing, free per m136).  Stores: 512B contiguous runs per chunk.
// ---------------------------------------------------------------------------
#define FC_RB 152
#define FC_WT_ST 1026
#define FC_HS_ST 154

__global__ __launch_bounds__(512, 1) void fc_out2(const float* __restrict__ H,
                                                  const float* __restrict__ W,
                                                  const float* __restrict__ bias,
                                                  float* __restrict__ Y) {
  extern __shared__ float sm[];
  float* Wt = sm;                     // [32][FC_WT_ST]
  float* Hs = sm + 32 * FC_WT_ST;     // [32][FC_HS_ST]
  const int tid = threadIdx.x;
  const int tc = tid & 127;           // col-pair index: cols 2*tc within chunk
  const int rt = tid >> 7;            // row-octet within 32-row pass (0..3)
  const int rbase = blockIdx.x * FC_RB;

  // stage H tile (152 rows x 32), transposed -> Hs[k][r]
  for (int i = tid; i < FC_RB * 8; i += 512) {
    int r = i >> 3, kq = i & 7;
    float4 v = *(const float4*)(H + (size_t)(rbase + r) * 32 + kq * 4);
    Hs[(kq * 4 + 0) * FC_HS_ST + r] = v.x;
    Hs[(kq * 4 + 1) * FC_HS_ST + r] = v.y;
    Hs[(kq * 4 + 2) * FC_HS_ST + r] = v.z;
    Hs[(kq * 4 + 3) * FC_HS_ST + r] = v.w;
  }

  for (int ph = 0; ph < 2; ++ph) {
    const int phbase = ph * 1024;
    const int ncols = (ph == 0) ? 1024 : 976;  // 1024+976 = 2000
    __syncthreads();  // (a) Hs ready on ph=0; (b) prior-phase Wt readers done
    // stage W cols [phbase, phbase+ncols), transposed -> Wt[k][c]
    for (int c = tid; c < ncols; c += 512) {
      const float* wrow = W + (size_t)(phbase + c) * 32;
#pragma unroll
      for (int q = 0; q < 8; ++q) {
        float4 v = *(const float4*)(wrow + q * 4);
        Wt[(q * 4 + 0) * FC_WT_ST + c] = v.x;
        Wt[(q * 4 + 1) * FC_WT_ST + c] = v.y;
        Wt[(q * 4 + 2) * FC_WT_ST + c] = v.z;
        Wt[(q * 4 + 3) * FC_WT_ST + c] = v.w;
      }
    }
    __syncthreads();

    float bq[4][2];
#pragma unroll
    for (int ch = 0; ch < 4; ++ch) {
      int col = phbase + ch * 256 + 2 * tc;
      bq[ch][0] = (col < 2000) ? bias[col] : 0.f;
      bq[ch][1] = (col < 2000) ? bias[col + 1] : 0.f;  // col even, 2000 even
    }

    for (int pass = 0; pass < 5; ++pass) {
      int r0 = pass * 32 + rt * 8;
      if (r0 + 8 > FC_RB) continue;  // wave-uniform (rt const per wave)
      float acc[8][8];
#pragma unroll
      for (int i = 0; i < 8; ++i)
#pragma unroll
        for (int j = 0; j < 8; ++j) acc[i][j] = 0.f;
#pragma unroll 8
      for (int k = 0; k < 32; ++k) {
        float4 ha = *(const float4*)&Hs[k * FC_HS_ST + r0];
        float4 hb = *(const float4*)&Hs[k * FC_HS_ST + r0 + 4];
        float hr[8] = {ha.x, ha.y, ha.z, ha.w, hb.x, hb.y, hb.z, hb.w};
        float2 w0 = *(const float2*)&Wt[k * FC_WT_ST + 0 * 256 + 2 * tc];
        float2 w1 = *(const float2*)&Wt[k * FC_WT_ST + 1 * 256 + 2 * tc];
        float2 w2 = *(const float2*)&Wt[k * FC_WT_ST + 2 * 256 + 2 * tc];
        float2 w3 = *(const float2*)&Wt[k * FC_WT_ST + 3 * 256 + 2 * tc];
        float wc[8] = {w0.x, w0.y, w1.x, w1.y, w2.x, w2.y, w3.x, w3.y};
#pragma unroll
        for (int i = 0; i < 8; ++i)
#pragma unroll
          for (int j = 0; j < 8; ++j) acc[i][j] = fmaf(hr[i], wc[j], acc[i][j]);
      }
#pragma unroll
      for (int i = 0; i < 8; ++i) {
        size_t row = (size_t)(rbase + r0 + i);
#pragma unroll
        for (int ch = 0; ch < 4; ++ch) {
          int col = phbase + ch * 256 + 2 * tc;
          if (col < 2000) {
            float2 v;
            v.x = acc[i][2 * ch + 0] + bq[ch][0];
            v.y = acc[i][2 * ch + 1] + bq[ch][1];
            *(float2*)(Y + row * 2000 + col) = v;
          }
        }
      }
    }
  }
}

// ---------------------------------------------------------------------------
extern "C" void kernel_launch(void* const* d_in, const int* in_sizes, int n_in,
                              void* d_out, int out_size, void* d_ws,
                              size_t ws_size, hipStream_t stream) {
  (void)in_sizes; (void)n_in; (void)out_size; (void)ws_size;
  const float* grid_embedding = (const float*)d_in[0];
  const float* grid_onehot = (const float*)d_in[1];
  const float* inventory = (const float*)d_in[2];
  const float* goal = (const float*)d_in[3];
  const int* captions = (const int*)d_in[4];
  // d_in[5] caption_length == 20 (hardcoded T=19)
  const float* W_embed = (const float*)d_in[6];
  const float* b_embed = (const float*)d_in[7];
  const float* W_onehot = (const float*)d_in[8];
  const float* b_onehot = (const float*)d_in[9];
  const float* W_inv = (const float*)d_in[10];
  const float* b_inv = (const float*)d_in[11];
  const float* W_goal = (const float*)d_in[12];
  const float* b_goal = (const float*)d_in[13];
  const float* W_enc_att = (const float*)d_in[14];
  const float* b_enc_att = (const float*)d_in[15];
  const float* W_dec_att = (const float*)d_in[16];
  const float* b_dec_att = (const float*)d_in[17];
  const float* W_full_att = (const float*)d_in[18];
  // d_in[19] b_full_att: softmax shift-invariant -> unused
  const float* emb_table = (const float*)d_in[20];
  const float* W_ih = (const float*)d_in[21];
  const float* b_ih = (const float*)d_in[22];
  const float* W_hh = (const float*)d_in[23];
  const float* b_hh = (const float*)d_in[24];
  const float* W_init_h = (const float*)d_in[25];
  const float* b_init_h = (const float*)d_in[26];
  const float* W_init_c = (const float*)d_in[27];
  const float* b_init_c = (const float*)d_in[28];
  const float* W_fbeta = (const float*)d_in[29];
  const float* b_fbeta = (const float*)d_in[30];
  const float* W_fc = (const float*)d_in[31];
  const float* b_fc = (const float*)d_in[32];

  float* out = (float*)d_out;
  float* preds = out;                              // 2048*19*2000
  float* alphas = out + (size_t)77824000;          // 2048*19*36
  float* houtp = out + (size_t)79224832;           // 2048*32

  float* ws = (float*)d_ws;
  float* ws_enc = ws;                              // 2048*36*128
  float* ws_att1 = ws_enc + (size_t)9437184;       // 2048*36*128
  float* ws_embW = ws_att1 + (size_t)9437184;      // 2048*19*128
  float* ws_H = ws_embW + (size_t)4980736;         // 2048*19*32
  float* ws_h0 = ws_H + (size_t)1245184;           // 2048*32
  float* ws_c0 = ws_h0 + (size_t)65536;            // 2048*32

  // encoder: grid (dual relu), inventory, goal
  lin_gemm<<<200, 256, 0, stream>>>(grid_embedding, 300, nullptr, W_embed, 300,
                                    300, b_embed, grid_onehot, W_onehot,
                                    b_onehot, ws_enc, 0, 1);
  lin_gemm<<<80, 256, 0, stream>>>(inventory, 300, nullptr, W_inv, 300, 300,
                                   b_inv, nullptr, nullptr, nullptr, ws_enc, 1, 1);
  lin_gemm<<<8, 256, 0, stream>>>(goal, 300, nullptr, W_goal, 300, 300, b_goal,
                                  nullptr, nullptr, nullptr, ws_enc, 2, 1);
  init_hc<<<2048, 64, 0, stream>>>(ws_enc, W_init_h, b_init_h, W_init_c,
                                   b_init_c, ws_h0, ws_c0);
  // att1 = enc @ W_enc_att.T + b
  lin_gemm<<<288, 256, 0, stream>>>(ws_enc, 128, nullptr, W_enc_att, 128, 128,
                                    b_enc_att, nullptr, nullptr, nullptr,
                                    ws_att1, 3, 0);
  // embW = emb_table[cap] @ W_ih[:, :300].T + b_ih
  lin_gemm<<<152, 256, 0, stream>>>(emb_table, 300, captions, W_ih, 300, 428,
                                    b_ih, nullptr, nullptr, nullptr, ws_embW, 3, 0);
  hipFuncSetAttribute((const void*)recurrent_k,
                      hipFuncAttributeMaxDynamicSharedMemorySize, 81920);
  recurrent_k<<<512, 256, 81920, stream>>>(
      ws_enc, ws_att1, ws_embW, ws_h0, ws_c0, W_dec_att, b_dec_att, W_full_att,
      W_ih, W_hh, b_hh, W_fbeta, b_fbeta, ws_H, alphas, houtp);
  hipFuncSetAttribute((const void*)fc_out2,
                      hipFuncAttributeMaxDynamicSharedMemorySize, 151040);
  fc_out2<<<256, 512, 151040, stream>>>(ws_H, W_fc, b_fc, preds);
}